// Round 6
// baseline (72.940 us; speedup 1.0000x reference)
//
#include <hip/hip_runtime.h>
#include <math.h>

#define BN 256      // batch
#define CN 2048     // channels
#define C4 512      // CN/4
#define EPSF 1e-12f

// ---------------------------------------------------------------------------
// Kernel A: raw Gram D = in @ in^T (256x256, K=2048), fp32, SYMMETRIC.
// Round 6: balanced unit-walk. Evidence chain: round 2's (256,2) regression
// proves natural VGPR > 256 -> occupancy 1 -> 288 kept blocks leave 32 CUs
// running TWO sequential 288-KB blocks (makespan ~4.3 us, not 2.4). Round
// 4 proved bigger per-block register footprints are fatal. Fix that keeps
// the register footprint of the round-3 body: the 288 tiles x 8 s-units =
// 2304 units = 256 x 9 exactly. 256 blocks; block b walks units 9b..9b+8.
// Unit u: tile t=u>>3 (jb via prefix compare, preA=4jb(jb+1) closed form;
// ib=t-preA), s=u&7; j = 32jb + wave + 4s. A block spans at most 2 tiles ->
// at most one a[4][8] reload (block-uniform). Per-CU traffic ~348 KB
// (9x32KB j + ~1.9x32KB a) vs 576 KB worst-case today -> makespan ~2.6 us.
// BITWISE: per-(tile,s) loads, FMA order, merge tree, D/mirror stores are
// byte-identical to round 3/5 -> D bit-identical. s_pre: the block owning
// (jb==7, s==7) of each center tile does the same s_ctr exchange + write
// (ascending-row add order); trailing barrier orders s_ctr reuse in the
// rare block that owns two consecutive jb==7 events. Block 0 zeroes out[0]
// at entry (ordered before finish by the kernel boundary).
// __launch_bounds__(256,1) kept: allocator freedom (round-2 lesson).
// ---------------------------------------------------------------------------
__global__ __launch_bounds__(256, 1) void gram_kernel(const float* __restrict__ in,
                                                      float* __restrict__ D,
                                                      float* __restrict__ s_pre,
                                                      float* __restrict__ out) {
    const int b    = blockIdx.x;
    const int tid  = threadIdx.x;
    const int lane = tid & 63;
    const int wave = tid >> 6;
    const bool odd1 = (lane & 1);
    const bool odd2 = (lane & 2);

    if (b == 0 && tid == 0) out[0] = 0.f;

    __shared__ float s_ctr[16];            // [wave*4 + r]: D[252+wave, i0+r]

    const float4* __restrict__ in4 = (const float4*)in;

    float4 a[4][8];
    int cur_ib = -1;

    const int u0 = 9 * b;
    for (int k = 0; k < 9; ++k) {
        const int u = u0 + k;
        const int t = u >> 3;
        const int s = u & 7;
        int jb = 0;
        jb += (t >= 8);   jb += (t >= 24);  jb += (t >= 48);  jb += (t >= 80);
        jb += (t >= 120); jb += (t >= 168); jb += (t >= 224);
        const int ib = t - 4 * jb * (jb + 1);     // preA[jb] = 4jb(jb+1)
        const int i0 = ib * 4;

        if (ib != cur_ib) {                 // block-uniform: <=2 per block
            cur_ib = ib;
#pragma unroll
            for (int r = 0; r < 4; ++r)
#pragma unroll
                for (int tt = 0; tt < 8; ++tt)
                    a[r][tt] = in4[(i0 + r) * C4 + lane + 64 * tt];
        }

        const int j = 32 * jb + wave + 4 * s;
        float4 bv[8];
#pragma unroll
        for (int tt = 0; tt < 8; ++tt)
            bv[tt] = in4[j * C4 + lane + 64 * tt];

        float a0 = 0.f, a1 = 0.f, a2 = 0.f, a3 = 0.f;
#pragma unroll
        for (int tt = 0; tt < 8; ++tt) {
            const float4 b4 = bv[tt];
            a0 += a[0][tt].x * b4.x + a[0][tt].y * b4.y + a[0][tt].z * b4.z + a[0][tt].w * b4.w;
            a1 += a[1][tt].x * b4.x + a[1][tt].y * b4.y + a[1][tt].z * b4.z + a[1][tt].w * b4.w;
            a2 += a[2][tt].x * b4.x + a[2][tt].y * b4.y + a[2][tt].z * b4.z + a[2][tt].w * b4.w;
            a3 += a[3][tt].x * b4.x + a[3][tt].y * b4.y + a[3][tt].z * b4.z + a[3][tt].w * b4.w;
        }

        // merge-tree reduction: 7 shuffles, lane r in {0..3} ends with acc r
        const float c01 = (odd1 ? a1 : a0) + __shfl_xor(odd1 ? a0 : a1, 1, 64);
        const float c23 = (odd1 ? a3 : a2) + __shfl_xor(odd1 ? a2 : a3, 1, 64);
        float c = (odd2 ? c23 : c01) + __shfl_xor(odd2 ? c01 : c23, 2, 64);
        c += __shfl_xor(c, 4, 64);
        c += __shfl_xor(c, 8, 64);
        c += __shfl_xor(c, 16, 64);
        c += __shfl_xor(c, 32, 64);

        if (lane < 4) {
            const int i = i0 + lane;
            D[i * BN + j] = c;
            D[j * BN + i] = c;             // mirror (bitwise-identical value)
            if (jb == 7 && s == 7)         // j = 252 + wave: center rows
                s_ctr[wave * 4 + lane] = c;
        }

        if (jb == 7 && s == 7) {           // block-uniform event
            __syncthreads();
            if (tid < 4) {
                // ascending center-row add order == original si loop -> bitwise
                const float sp = (((s_ctr[tid] + s_ctr[4 + tid]) + s_ctr[8 + tid])
                                  + s_ctr[12 + tid]) * 0.25f;
                s_pre[i0 + tid] = sp;
            }
            __syncthreads();               // orders s_ctr reuse (2-event blocks)
        }
    }
}

// ---------------------------------------------------------------------------
// Kernel B: loss from D. Grid 8 x 256; block handles 32 rows.
// UNCHANGED from round 5 (bitwise-identical output; isolates the gram A/B):
// single-sync preamble, all global loads front-loaded into one latency
// window; cc per-thread from s_pre[252..255] (ascending order); inv and invR
// computed locally (identical expressions -> identical bits); coalesced
// j4 = q*8+sub main pass; shuffle reductions; 8-block atomicAdd.
// ---------------------------------------------------------------------------
__global__ __launch_bounds__(256) void finish_kernel(const float* __restrict__ D,
                                                     const float* __restrict__ s_pre,
                                                     const int* __restrict__ targets,
                                                     float* __restrict__ out) {
    const int tid = threadIdx.x;
    const int blk = blockIdx.x;

    __shared__ int   s_t[BN];
    __shared__ float s_s[BN];
    __shared__ float s_inv[BN];
    __shared__ float s_red[4];

    const int row = blk * 32 + (tid >> 3);
    const int sub = tid & 7;

    // ---- all global loads issued up front (one latency window) ----
    const float4* __restrict__ D4 = (const float4*)D;
    float4 drow[8];
#pragma unroll
    for (int q = 0; q < 8; ++q)
        drow[q] = D4[row * (BN / 4) + q * 8 + sub];

    const int   t_own = targets[tid];
    const float dii   = D[tid * BN + tid];
    const float si    = s_pre[tid];
    const int   ti    = targets[row];
    const float diiR  = D[row * BN + row];
    const float siR   = s_pre[row];
    const float sp0   = s_pre[BN - 4];
    const float sp1   = s_pre[BN - 3];
    const float sp2   = s_pre[BN - 2];
    const float sp3   = s_pre[BN - 1];

    // cc: same ascending-row add order as always -> bitwise equal
    const float cc = (((sp0 + sp1) + sp2) + sp3) * 0.25f;

    // own inverse norm (published for the j side)
    const float nrm2 = fmaxf(dii - 2.f * si + cc, 0.f);
    const float inv  = 1.0f / fmaxf(sqrtf(nrm2), EPSF);
    // row inverse norm, computed locally: identical expression on identical
    // inputs -> bitwise identical to the old s_inv[row]
    const float nrm2R = fmaxf(diiR - 2.f * siR + cc, 0.f);
    const float invR  = 1.0f / fmaxf(sqrtf(nrm2R), EPSF);

    s_t[tid]   = t_own;
    s_s[tid]   = si;
    s_inv[tid] = inv;
    __syncthreads();                        // the only barrier

    float pos = INFINITY;
    float neg = 0.f;
#pragma unroll
    for (int q = 0; q < 8; ++q) {
        const float4 d = drow[q];
        const int j = 4 * (q * 8 + sub);
        const float g0 = (d.x - siR - s_s[j + 0] + cc) * invR * s_inv[j + 0];
        const float g1 = (d.y - siR - s_s[j + 1] + cc) * invR * s_inv[j + 1];
        const float g2 = (d.z - siR - s_s[j + 2] + cc) * invR * s_inv[j + 2];
        const float g3 = (d.w - siR - s_s[j + 3] + cc) * invR * s_inv[j + 3];
        if (s_t[j + 0] == ti) pos = fminf(pos, g0); else neg = fmaxf(neg, fmaxf(g0, 0.f));
        if (s_t[j + 1] == ti) pos = fminf(pos, g1); else neg = fmaxf(neg, fmaxf(g1, 0.f));
        if (s_t[j + 2] == ti) pos = fminf(pos, g2); else neg = fmaxf(neg, fmaxf(g2, 0.f));
        if (s_t[j + 3] == ti) pos = fminf(pos, g3); else neg = fmaxf(neg, fmaxf(g3, 0.f));
    }
    // reduce pos/neg across the 8 sub-threads of this row (contiguous lanes)
#pragma unroll
    for (int off = 1; off <= 4; off <<= 1) {
        pos = fminf(pos, __shfl_xor(pos, off, 64));
        neg = fmaxf(neg, __shfl_xor(neg, off, 64));
    }
    float val = (sub == 0) ? expf(neg - pos) : 0.f;
#pragma unroll
    for (int off = 1; off <= 32; off <<= 1) val += __shfl_xor(val, off, 64);
    if ((tid & 63) == 0) s_red[tid >> 6] = val;
    __syncthreads();
    if (tid == 0)
        atomicAdd(out, (s_red[0] + s_red[1] + s_red[2] + s_red[3]) * (1.0f / 448.0f));
}

extern "C" void kernel_launch(void* const* d_in, const int* in_sizes, int n_in,
                              void* d_out, int out_size, void* d_ws, size_t ws_size,
                              hipStream_t stream) {
    const float* in      = (const float*)d_in[0];
    const int*   targets = (const int*)d_in[1];
    // d_in[2] (subs) is unused by the reference.

    float* D     = (float*)d_ws;             // 256*256 floats = 256 KB
    float* s_pre = D + BN * BN;              // 256 floats
    float* out   = (float*)d_out;

    gram_kernel  <<<256, 256, 0, stream>>>(in, D, s_pre, out);
    finish_kernel<<<8,   256, 0, stream>>>(D, s_pre, targets, out);
}

// Round 7
// 72.638 us; speedup vs baseline: 1.0042x; 1.0042x over previous
//
#include <hip/hip_runtime.h>
#include <math.h>

#define BN 256      // batch
#define CN 2048     // channels
#define C4 512      // CN/4
#define EPSF 1e-12f

// ---------------------------------------------------------------------------
// Kernel A: raw Gram D = in @ in^T (256x256, K=2048), fp32, SYMMETRIC.
// Round 7: tail split, prologue-only mapping. Round-6 post-mortem: per-unit
// dynamic mapping inside the hot loop killed bv-load pipelining (+2.2 us).
// This version keeps the round-3/5 inner body BYTE-IDENTICAL and static:
//   * blocks 0..255   = kept tiles t=0..255, all 8 s-iters (exact round-3
//     loop, #pragma unroll 2, static bounds).
//   * blocks 256..383 = kept tiles t=256..287 (the 32 tiles that previously
//     forced 32 CUs into a second full 288-KB round) split into 4 quarter
//     blocks each: 2 s-iters, 96 KB, ~0.7 us. Small tail blocks backfill
//     freed CUs immediately -> gram makespan ~4.3 -> ~2.9 us.
// Mapping (once per block, prologue): kept-tile id t -> jb = #prefix
// compares (prefix 4jb(jb+1): counts 8jb+8 per jb, total 288), ib = t -
// 4jb(jb+1). Kept condition ib <= 8jb+7 holds for t < 288 by construction.
// BITWISE: per-(tile,s) j-loads, FMA order, 7-shuffle merge tree, D +
// mirror stores identical to round 3/5 -> D bit-identical. s_pre emission:
// full blocks with jb==7 (t 224..255 -> ib 0..31) at s==7; tail quarters
// with s_lo==6 (s covers 7) for ib 32..63 — same s_ctr exchange, same
// ascending-row add order -> bitwise equal. Block 0 zeroes out[0] at entry
// (kernel boundary orders it before finish).
// __launch_bounds__(256,1) kept: allocator freedom (round-2 lesson).
// ---------------------------------------------------------------------------
__device__ __forceinline__ void gram_unit(const float4* __restrict__ in4,
                                          const float4 (&a)[4][8],
                                          float* __restrict__ D,
                                          float* __restrict__ s_ctr,
                                          const int i0, const int j0,
                                          const int jb, const int s,
                                          const int lane, const int wave,
                                          const bool odd1, const bool odd2) {
    const int j = j0 + wave + 4 * s;
    float4 bv[8];
#pragma unroll
    for (int tt = 0; tt < 8; ++tt)
        bv[tt] = in4[j * C4 + lane + 64 * tt];

    float a0 = 0.f, a1 = 0.f, a2 = 0.f, a3 = 0.f;
#pragma unroll
    for (int tt = 0; tt < 8; ++tt) {
        const float4 b4 = bv[tt];
        a0 += a[0][tt].x * b4.x + a[0][tt].y * b4.y + a[0][tt].z * b4.z + a[0][tt].w * b4.w;
        a1 += a[1][tt].x * b4.x + a[1][tt].y * b4.y + a[1][tt].z * b4.z + a[1][tt].w * b4.w;
        a2 += a[2][tt].x * b4.x + a[2][tt].y * b4.y + a[2][tt].z * b4.z + a[2][tt].w * b4.w;
        a3 += a[3][tt].x * b4.x + a[3][tt].y * b4.y + a[3][tt].z * b4.z + a[3][tt].w * b4.w;
    }

    // merge-tree reduction: 7 shuffles, lane r in {0..3} ends with acc r
    const float c01 = (odd1 ? a1 : a0) + __shfl_xor(odd1 ? a0 : a1, 1, 64);
    const float c23 = (odd1 ? a3 : a2) + __shfl_xor(odd1 ? a2 : a3, 1, 64);
    float c = (odd2 ? c23 : c01) + __shfl_xor(odd2 ? c01 : c23, 2, 64);
    c += __shfl_xor(c, 4, 64);
    c += __shfl_xor(c, 8, 64);
    c += __shfl_xor(c, 16, 64);
    c += __shfl_xor(c, 32, 64);

    if (lane < 4) {
        const int i = i0 + lane;
        D[i * BN + j] = c;
        D[j * BN + i] = c;                 // mirror (bitwise-identical value)
        if (jb == 7 && s == 7)             // j = 252 + wave: center rows
            s_ctr[wave * 4 + lane] = c;
    }
}

__global__ __launch_bounds__(256, 1) void gram_kernel(const float* __restrict__ in,
                                                      float* __restrict__ D,
                                                      float* __restrict__ s_pre,
                                                      float* __restrict__ out) {
    const int b    = blockIdx.x;
    const int tid  = threadIdx.x;
    const int lane = tid & 63;
    const int wave = tid >> 6;
    const bool odd1 = (lane & 1);
    const bool odd2 = (lane & 2);

    if (b == 0 && tid == 0) out[0] = 0.f;

    // ---- prologue-only mapping ----
    int t, s_lo;
    if (b < 256) { t = b;                      s_lo = 0; }
    else         { t = 256 + ((b - 256) >> 2); s_lo = ((b - 256) & 3) << 1; }
    int jb = 0;
    jb += (t >= 8);   jb += (t >= 24);  jb += (t >= 48);  jb += (t >= 80);
    jb += (t >= 120); jb += (t >= 168); jb += (t >= 224);
    const int ib = t - 4 * jb * (jb + 1);      // prefix = 4jb(jb+1)
    const int i0 = ib * 4;
    const int j0 = jb * 32;

    __shared__ float s_ctr[16];            // [wave*4 + r]: D[252+wave, i0+r]

    const float4* __restrict__ in4 = (const float4*)in;

    float4 a[4][8];
#pragma unroll
    for (int r = 0; r < 4; ++r)
#pragma unroll
        for (int tt = 0; tt < 8; ++tt)
            a[r][tt] = in4[(i0 + r) * C4 + lane + 64 * tt];

    if (b < 256) {
        // exact round-3/5 static loop
#pragma unroll 2
        for (int s = 0; s < 8; ++s)
            gram_unit(in4, a, D, s_ctr, i0, j0, jb, s, lane, wave, odd1, odd2);
    } else {
        gram_unit(in4, a, D, s_ctr, i0, j0, jb, s_lo,     lane, wave, odd1, odd2);
        gram_unit(in4, a, D, s_ctr, i0, j0, jb, s_lo + 1, lane, wave, odd1, odd2);
    }

    if (jb == 7 && (b < 256 || s_lo == 6)) {   // block-uniform; s range hit 7
        __syncthreads();
        if (tid < 4) {
            // ascending center-row add order == original si loop -> bitwise
            const float sp = (((s_ctr[tid] + s_ctr[4 + tid]) + s_ctr[8 + tid])
                              + s_ctr[12 + tid]) * 0.25f;
            s_pre[i0 + tid] = sp;
        }
    }
}

// ---------------------------------------------------------------------------
// Kernel B: loss from D. Grid 8 x 256; block handles 32 rows.
// UNCHANGED from round 5 (known-best; bitwise-identical output): single-sync
// preamble, all global loads front-loaded into one latency window; cc
// per-thread from s_pre[252..255] (ascending order); inv and invR computed
// locally (identical expressions -> identical bits); coalesced j4 = q*8+sub
// main pass; shuffle reductions; 8-block atomicAdd.
// ---------------------------------------------------------------------------
__global__ __launch_bounds__(256) void finish_kernel(const float* __restrict__ D,
                                                     const float* __restrict__ s_pre,
                                                     const int* __restrict__ targets,
                                                     float* __restrict__ out) {
    const int tid = threadIdx.x;
    const int blk = blockIdx.x;

    __shared__ int   s_t[BN];
    __shared__ float s_s[BN];
    __shared__ float s_inv[BN];
    __shared__ float s_red[4];

    const int row = blk * 32 + (tid >> 3);
    const int sub = tid & 7;

    // ---- all global loads issued up front (one latency window) ----
    const float4* __restrict__ D4 = (const float4*)D;
    float4 drow[8];
#pragma unroll
    for (int q = 0; q < 8; ++q)
        drow[q] = D4[row * (BN / 4) + q * 8 + sub];

    const int   t_own = targets[tid];
    const float dii   = D[tid * BN + tid];
    const float si    = s_pre[tid];
    const int   ti    = targets[row];
    const float diiR  = D[row * BN + row];
    const float siR   = s_pre[row];
    const float sp0   = s_pre[BN - 4];
    const float sp1   = s_pre[BN - 3];
    const float sp2   = s_pre[BN - 2];
    const float sp3   = s_pre[BN - 1];

    // cc: same ascending-row add order as always -> bitwise equal
    const float cc = (((sp0 + sp1) + sp2) + sp3) * 0.25f;

    // own inverse norm (published for the j side)
    const float nrm2 = fmaxf(dii - 2.f * si + cc, 0.f);
    const float inv  = 1.0f / fmaxf(sqrtf(nrm2), EPSF);
    // row inverse norm, computed locally: identical expression on identical
    // inputs -> bitwise identical to the old s_inv[row]
    const float nrm2R = fmaxf(diiR - 2.f * siR + cc, 0.f);
    const float invR  = 1.0f / fmaxf(sqrtf(nrm2R), EPSF);

    s_t[tid]   = t_own;
    s_s[tid]   = si;
    s_inv[tid] = inv;
    __syncthreads();                        // the only barrier

    float pos = INFINITY;
    float neg = 0.f;
#pragma unroll
    for (int q = 0; q < 8; ++q) {
        const float4 d = drow[q];
        const int j = 4 * (q * 8 + sub);
        const float g0 = (d.x - siR - s_s[j + 0] + cc) * invR * s_inv[j + 0];
        const float g1 = (d.y - siR - s_s[j + 1] + cc) * invR * s_inv[j + 1];
        const float g2 = (d.z - siR - s_s[j + 2] + cc) * invR * s_inv[j + 2];
        const float g3 = (d.w - siR - s_s[j + 3] + cc) * invR * s_inv[j + 3];
        if (s_t[j + 0] == ti) pos = fminf(pos, g0); else neg = fmaxf(neg, fmaxf(g0, 0.f));
        if (s_t[j + 1] == ti) pos = fminf(pos, g1); else neg = fmaxf(neg, fmaxf(g1, 0.f));
        if (s_t[j + 2] == ti) pos = fminf(pos, g2); else neg = fmaxf(neg, fmaxf(g2, 0.f));
        if (s_t[j + 3] == ti) pos = fminf(pos, g3); else neg = fmaxf(neg, fmaxf(g3, 0.f));
    }
    // reduce pos/neg across the 8 sub-threads of this row (contiguous lanes)
#pragma unroll
    for (int off = 1; off <= 4; off <<= 1) {
        pos = fminf(pos, __shfl_xor(pos, off, 64));
        neg = fmaxf(neg, __shfl_xor(neg, off, 64));
    }
    float val = (sub == 0) ? expf(neg - pos) : 0.f;
#pragma unroll
    for (int off = 1; off <= 32; off <<= 1) val += __shfl_xor(val, off, 64);
    if ((tid & 63) == 0) s_red[tid >> 6] = val;
    __syncthreads();
    if (tid == 0)
        atomicAdd(out, (s_red[0] + s_red[1] + s_red[2] + s_red[3]) * (1.0f / 448.0f));
}

extern "C" void kernel_launch(void* const* d_in, const int* in_sizes, int n_in,
                              void* d_out, int out_size, void* d_ws, size_t ws_size,
                              hipStream_t stream) {
    const float* in      = (const float*)d_in[0];
    const int*   targets = (const int*)d_in[1];
    // d_in[2] (subs) is unused by the reference.

    float* D     = (float*)d_ws;             // 256*256 floats = 256 KB
    float* s_pre = D + BN * BN;              // 256 floats
    float* out   = (float*)d_out;

    gram_kernel  <<<384, 256, 0, stream>>>(in, D, s_pre, out);
    finish_kernel<<<8,   256, 0, stream>>>(D, s_pre, targets, out);
}

// Round 8
// 70.815 us; speedup vs baseline: 1.0300x; 1.0257x over previous
//
#include <hip/hip_runtime.h>
#include <math.h>

#define BN 256      // batch
#define CN 2048     // channels
#define C4 512      // CN/4
#define EPSF 1e-12f

// ---------------------------------------------------------------------------
// Kernel A: raw Gram D = in @ in^T (256x256, K=2048), fp32, SYMMETRIC.
// FINAL: exact round-5 known-best (70.76 us). Rounds 4/6/7 each tried to
// recover the 32-CU tail (bigger tiles / balanced unit-walk / split tail
// blocks) and ALL regressed ~+2 us: the compiler's schedule for THIS literal
// loop (pipelined bv loads across the unroll-2 s-loop, flat a[4][8]) is
// load-bearing and does not survive structural edits. Round 2 proved VGPR
// caps are worse still. 4i x 32j / 288 kept blocks / occupancy 1 stands.
// Tiles: ib=b>>3 (4 i-rows), jb=b&7 (32 j-cols); strict-lower tiles exit
// early (mirror-covered). Block 64 (exit) zeroes out[0]. jb==7 blocks emit
// s_pre[i] = (((D[252,i]+D[253,i])+D[254,i])+D[255,i])*0.25 from their s==7
// column (ascending-row add order == original finish si loop -> bitwise).
// ---------------------------------------------------------------------------
__global__ __launch_bounds__(256, 1) void gram_kernel(const float* __restrict__ in,
                                                      float* __restrict__ D,
                                                      float* __restrict__ s_pre,
                                                      float* __restrict__ out) {
    const int b   = blockIdx.x;
    const int ib  = b >> 3;
    const int jb  = b & 7;
    const int tid = threadIdx.x;

    if (32 * jb + 31 < 4 * ib) {           // strictly-lower tile: mirror-covered
        if (b == 64 && tid == 0) out[0] = 0.f;
        return;
    }

    const int i0   = ib * 4;
    const int j0   = jb * 32;
    const int lane = tid & 63;
    const int wave = tid >> 6;
    const bool odd1 = (lane & 1);
    const bool odd2 = (lane & 2);

    __shared__ float s_ctr[16];            // [wave*4 + r]: D[252+wave, i0+r]

    const float4* __restrict__ in4 = (const float4*)in;

    float4 a[4][8];
#pragma unroll
    for (int r = 0; r < 4; ++r)
#pragma unroll
        for (int t = 0; t < 8; ++t)
            a[r][t] = in4[(i0 + r) * C4 + lane + 64 * t];

#pragma unroll 2
    for (int s = 0; s < 8; ++s) {
        const int j = j0 + wave + 4 * s;
        float4 bv[8];
#pragma unroll
        for (int t = 0; t < 8; ++t)
            bv[t] = in4[j * C4 + lane + 64 * t];

        float a0 = 0.f, a1 = 0.f, a2 = 0.f, a3 = 0.f;
#pragma unroll
        for (int t = 0; t < 8; ++t) {
            const float4 b4 = bv[t];
            a0 += a[0][t].x * b4.x + a[0][t].y * b4.y + a[0][t].z * b4.z + a[0][t].w * b4.w;
            a1 += a[1][t].x * b4.x + a[1][t].y * b4.y + a[1][t].z * b4.z + a[1][t].w * b4.w;
            a2 += a[2][t].x * b4.x + a[2][t].y * b4.y + a[2][t].z * b4.z + a[2][t].w * b4.w;
            a3 += a[3][t].x * b4.x + a[3][t].y * b4.y + a[3][t].z * b4.z + a[3][t].w * b4.w;
        }

        // merge-tree reduction: 7 shuffles, lane r in {0..3} ends with acc r
        const float c01 = (odd1 ? a1 : a0) + __shfl_xor(odd1 ? a0 : a1, 1, 64);
        const float c23 = (odd1 ? a3 : a2) + __shfl_xor(odd1 ? a2 : a3, 1, 64);
        float c = (odd2 ? c23 : c01) + __shfl_xor(odd2 ? c01 : c23, 2, 64);
        c += __shfl_xor(c, 4, 64);
        c += __shfl_xor(c, 8, 64);
        c += __shfl_xor(c, 16, 64);
        c += __shfl_xor(c, 32, 64);

        if (lane < 4) {
            const int i = i0 + lane;
            D[i * BN + j] = c;
            D[j * BN + i] = c;             // mirror (bitwise-identical value)
            if (jb == 7 && s == 7)         // j = 252 + wave: center rows
                s_ctr[wave * 4 + lane] = c;
        }
    }

    if (jb == 7) {                          // block-uniform branch
        __syncthreads();
        if (tid < 4) {
            // ascending center-row add order == old finish si loop -> bitwise
            const float sp = (((s_ctr[tid] + s_ctr[4 + tid]) + s_ctr[8 + tid])
                              + s_ctr[12 + tid]) * 0.25f;
            s_pre[i0 + tid] = sp;
        }
    }
}

// ---------------------------------------------------------------------------
// Kernel B: loss from D. Grid 8 x 256; block handles 32 rows.
// FINAL: round-5 single-sync preamble + front-loaded latency. All global
// loads (8x float4 D-row, own diag/s_pre, row's targets/diag/s_pre, the 4
// center s_pre values) issue at kernel entry into one overlapped latency
// window. cc per-thread from s_pre[252..255] (same ascending add order ->
// bitwise). inv/invR computed locally (identical expressions -> identical
// bits). One __syncthreads; coalesced j4 = q*8+sub main pass; shfl_xor
// reductions; 8-block atomicAdd into out[0] (zeroed by gram's block 64).
// ---------------------------------------------------------------------------
__global__ __launch_bounds__(256) void finish_kernel(const float* __restrict__ D,
                                                     const float* __restrict__ s_pre,
                                                     const int* __restrict__ targets,
                                                     float* __restrict__ out) {
    const int tid = threadIdx.x;
    const int blk = blockIdx.x;

    __shared__ int   s_t[BN];
    __shared__ float s_s[BN];
    __shared__ float s_inv[BN];
    __shared__ float s_red[4];

    const int row = blk * 32 + (tid >> 3);
    const int sub = tid & 7;

    // ---- all global loads issued up front (one latency window) ----
    const float4* __restrict__ D4 = (const float4*)D;
    float4 drow[8];
#pragma unroll
    for (int q = 0; q < 8; ++q)
        drow[q] = D4[row * (BN / 4) + q * 8 + sub];

    const int   t_own = targets[tid];
    const float dii   = D[tid * BN + tid];
    const float si    = s_pre[tid];
    const int   ti    = targets[row];
    const float diiR  = D[row * BN + row];
    const float siR   = s_pre[row];
    const float sp0   = s_pre[BN - 4];
    const float sp1   = s_pre[BN - 3];
    const float sp2   = s_pre[BN - 2];
    const float sp3   = s_pre[BN - 1];

    // cc: same ascending-row add order as always -> bitwise equal
    const float cc = (((sp0 + sp1) + sp2) + sp3) * 0.25f;

    // own inverse norm (published for the j side)
    const float nrm2 = fmaxf(dii - 2.f * si + cc, 0.f);
    const float inv  = 1.0f / fmaxf(sqrtf(nrm2), EPSF);
    // row inverse norm, computed locally: identical expression on identical
    // inputs -> bitwise identical to the old s_inv[row]
    const float nrm2R = fmaxf(diiR - 2.f * siR + cc, 0.f);
    const float invR  = 1.0f / fmaxf(sqrtf(nrm2R), EPSF);

    s_t[tid]   = t_own;
    s_s[tid]   = si;
    s_inv[tid] = inv;
    __syncthreads();                        // the only barrier

    float pos = INFINITY;
    float neg = 0.f;
#pragma unroll
    for (int q = 0; q < 8; ++q) {
        const float4 d = drow[q];
        const int j = 4 * (q * 8 + sub);
        const float g0 = (d.x - siR - s_s[j + 0] + cc) * invR * s_inv[j + 0];
        const float g1 = (d.y - siR - s_s[j + 1] + cc) * invR * s_inv[j + 1];
        const float g2 = (d.z - siR - s_s[j + 2] + cc) * invR * s_inv[j + 2];
        const float g3 = (d.w - siR - s_s[j + 3] + cc) * invR * s_inv[j + 3];
        if (s_t[j + 0] == ti) pos = fminf(pos, g0); else neg = fmaxf(neg, fmaxf(g0, 0.f));
        if (s_t[j + 1] == ti) pos = fminf(pos, g1); else neg = fmaxf(neg, fmaxf(g1, 0.f));
        if (s_t[j + 2] == ti) pos = fminf(pos, g2); else neg = fmaxf(neg, fmaxf(g2, 0.f));
        if (s_t[j + 3] == ti) pos = fminf(pos, g3); else neg = fmaxf(neg, fmaxf(g3, 0.f));
    }
    // reduce pos/neg across the 8 sub-threads of this row (contiguous lanes)
#pragma unroll
    for (int off = 1; off <= 4; off <<= 1) {
        pos = fminf(pos, __shfl_xor(pos, off, 64));
        neg = fmaxf(neg, __shfl_xor(neg, off, 64));
    }
    float val = (sub == 0) ? expf(neg - pos) : 0.f;
#pragma unroll
    for (int off = 1; off <= 32; off <<= 1) val += __shfl_xor(val, off, 64);
    if ((tid & 63) == 0) s_red[tid >> 6] = val;
    __syncthreads();
    if (tid == 0)
        atomicAdd(out, (s_red[0] + s_red[1] + s_red[2] + s_red[3]) * (1.0f / 448.0f));
}

extern "C" void kernel_launch(void* const* d_in, const int* in_sizes, int n_in,
                              void* d_out, int out_size, void* d_ws, size_t ws_size,
                              hipStream_t stream) {
    const float* in      = (const float*)d_in[0];
    const int*   targets = (const int*)d_in[1];
    // d_in[2] (subs) is unused by the reference.

    float* D     = (float*)d_ws;             // 256*256 floats = 256 KB
    float* s_pre = D + BN * BN;              // 256 floats
    float* out   = (float*)d_out;

    gram_kernel  <<<512, 256, 0, stream>>>(in, D, s_pre, out);
    finish_kernel<<<8,   256, 0, stream>>>(D, s_pre, targets, out);
}